// Round 3
// baseline (562.721 us; speedup 1.0000x reference)
//
#include <hip/hip_runtime.h>
#include <hip/hip_cooperative_groups.h>

namespace cg = cooperative_groups;

#define L_ 8
#define B_ 16
#define D_ 1024
#define JT 32              // output-column tile per block
#define IG 8               // i-groups per block
#define ILEN (D_ / IG)     // 128 reduction rows per i-group
#define PF 16              // W rows prefetched across the grid barrier
#define NBLK (B_ * (D_ / JT))   // 512 blocks = 2/CU

__global__ __launch_bounds__(256, 2) void discocirc_persist(
    const float* __restrict__ x,
    const float* __restrict__ W,    // [L][B][D][D]
    const float* __restrict__ Bs,   // [L][B][D]
    const int*   __restrict__ M,    // [L][B][D]
    float* __restrict__ out,        // [B][D]
    float* __restrict__ ws)         // 2 * B*D floats (h ping-pong)
{
    cg::grid_group grid = cg::this_grid();
    const int b   = blockIdx.x / (D_ / JT);
    const int jt  = blockIdx.x % (D_ / JT);
    const int tid = threadIdx.x;
    const int jl  = tid & 31;       // lane within j-tile
    const int ig  = tid >> 5;       // i-group 0..7

    __shared__ float hs[D_];
    __shared__ float red[IG][JT];

    float* hA = ws;
    float* hB = ws + B_ * D_;

    const size_t wstride = (size_t)D_ * D_;
    // This thread's W column pointer within layer 0 / sample b:
    const float* W0 = W + (size_t)b * wstride
                    + (size_t)(ig * ILEN) * D_ + jt * JT + jl;

    // Prefetch layer 0's first PF rows.
    float pf[PF];
#pragma unroll
    for (int p = 0; p < PF; ++p) pf[p] = W0[(size_t)p * D_];

    const float* hin = x;
    for (int l = 0; l < L_; ++l) {
        // Stage h[b,:] in LDS (256 x float4 = 4 KB).
        ((float4*)hs)[tid] = ((const float4*)(hin + (size_t)b * D_))[tid];
        __syncthreads();

        const float* Wp = W0 + (size_t)l * B_ * wstride;
        const float* hp = hs + ig * ILEN;

        float acc = 0.f;
#pragma unroll
        for (int i = 0; i < PF; ++i) acc += hp[i] * pf[i];
#pragma unroll 16
        for (int i = PF; i < ILEN; ++i) acc += hp[i] * Wp[(size_t)i * D_];

        // Issue next layer's prefetch BEFORE the grid barrier — W is
        // independent of h, so these loads overlap the sync spin.
        if (l + 1 < L_) {
            const float* Wn = Wp + (size_t)B_ * wstride;
#pragma unroll
            for (int p = 0; p < PF; ++p) pf[p] = Wn[(size_t)p * D_];
        }

        red[ig][jl] = acc;
        __syncthreads();

        float* hout = (l == L_ - 1) ? out : ((l & 1) ? hB : hA);
        if (tid < JT) {
            const int t = b * D_ + jt * JT + tid;
            float s = Bs[(size_t)l * B_ * D_ + t];
#pragma unroll
            for (int g = 0; g < IG; ++g) s += red[g][tid];
            if (M[(size_t)l * B_ * D_ + t]) s = fmaxf(s, 0.f);
            hout[t] = s;
        }
        hin = (l & 1) ? hB : hA;

        if (l + 1 < L_) grid.sync();
    }
}

extern "C" void kernel_launch(void* const* d_in, const int* in_sizes, int n_in,
                              void* d_out, int out_size, void* d_ws, size_t ws_size,
                              hipStream_t stream) {
    const float* x  = (const float*)d_in[0];
    const float* W  = (const float*)d_in[1];
    const float* Bs = (const float*)d_in[2];
    const int*   M  = (const int*)d_in[3];
    float* out = (float*)d_out;
    float* ws  = (float*)d_ws;

    void* args[] = { (void*)&x, (void*)&W, (void*)&Bs, (void*)&M,
                     (void*)&out, (void*)&ws };
    hipLaunchCooperativeKernel((const void*)discocirc_persist,
                               dim3(NBLK), dim3(256), args, 0, stream);
}